// Round 1
// baseline (311.818 us; speedup 1.0000x reference)
//
#include <hip/hip_runtime.h>
#include <hip/hip_bf16.h>

#define N_NODES 100000
#define N_EDGES 262144
#define IN_DIM 768
#define HIDDEN 256
#define BM 128
#define BN 256
#define BK 64
#define M_BLOCKS 782          // ceil(100000/128)
#define M_PAD (M_BLOCKS * BM) // 100096

typedef __attribute__((ext_vector_type(8))) short short8;
typedef __attribute__((ext_vector_type(4))) float f32x4;

__device__ __forceinline__ unsigned short f32_to_bf16(float f) {
    unsigned int u = __builtin_bit_cast(unsigned int, f);
    u = (u + 0x7FFFu + ((u >> 16) & 1u)) >> 16;
    return (unsigned short)u;
}
__device__ __forceinline__ float bf16_to_f32(unsigned short h) {
    unsigned int u = ((unsigned int)h) << 16;
    return __builtin_bit_cast(float, u);
}

// Wt[g][n][k] = bf16(W1[g*768 + k][n]) ; k-contiguous for 16B fragment reads
__global__ __launch_bounds__(256) void convert_w1(const float* __restrict__ W1,
                                                  unsigned short* __restrict__ Wt) {
    int t = blockIdx.x * blockDim.x + threadIdx.x;
    if (t >= 2 * HIDDEN * IN_DIM) return;
    int k = t % IN_DIM;
    int n = (t / IN_DIM) % HIDDEN;
    int g = t / (IN_DIM * HIDDEN);
    Wt[t] = f32_to_bf16(W1[(size_t)(g * IN_DIM + k) * HIDDEN + n]);
}

// One 128x256 output tile of P = bf16(X) @ bf16(W1half). K = 768.
// blockIdx.y selects (x_src, W1[:768], P) vs (x_dst, W1[768:], Q).
__global__ __launch_bounds__(512) void node_gemm(const float* __restrict__ X0,
                                                 const float* __restrict__ X1,
                                                 const unsigned short* __restrict__ WtAll,
                                                 unsigned short* __restrict__ Pout,
                                                 unsigned short* __restrict__ Qout) {
    const int g = blockIdx.y;
    const float* __restrict__ X = g ? X1 : X0;
    const unsigned short* __restrict__ Wt = WtAll + (size_t)g * IN_DIM * HIDDEN;
    unsigned short* __restrict__ Out = g ? Qout : Pout;

    // swizzled tiles: byte ^= ((row&7)<<4), row stride 128B
    __shared__ unsigned short As[BM * BK]; // [128][64] bf16, 16KB
    __shared__ unsigned short Bs[BN * BK]; // [256][64] bf16 (n-major, k-contig), 32KB

    const int m0   = blockIdx.x * BM;
    const int tid  = threadIdx.x;
    const int lane = tid & 63;
    const int wid  = tid >> 6;
    const int wm   = wid >> 2; // 0..1 -> 64-row slab
    const int wn   = wid & 3;  // 0..3 -> 64-col slab

    f32x4 acc[4][4] = {};

    for (int ks = 0; ks < IN_DIM / BK; ++ks) {
        const int k0 = ks * BK;
        // ---- stage A: 128 rows x 64 f32 -> bf16, 2048 float4 chunks, 4/thread
#pragma unroll
        for (int pass = 0; pass < 4; ++pass) {
            int c = pass * 512 + tid;
            int r = c >> 4;      // 0..127
            int p = c & 15;      // float4 index within row
            int rg = m0 + r;
            if (rg >= N_NODES) rg = N_NODES - 1; // clamp (pad rows get copies)
            float4 v = *(const float4*)(X + (size_t)rg * IN_DIM + k0 + p * 4);
            ushort4 w;
            w.x = f32_to_bf16(v.x); w.y = f32_to_bf16(v.y);
            w.z = f32_to_bf16(v.z); w.w = f32_to_bf16(v.w);
            *(ushort4*)((char*)As + r * 128 + ((p * 8) ^ ((r & 7) << 4))) = w;
        }
        // ---- stage B: 256 n-rows x 64 k -> 2048 16B chunks, 4/thread
#pragma unroll
        for (int pass = 0; pass < 4; ++pass) {
            int c = pass * 512 + tid;
            int n = c >> 3;     // 0..255
            int p = c & 7;      // 16B chunk within row
            short8 v = *(const short8*)(Wt + (size_t)n * IN_DIM + k0 + p * 8);
            *(short8*)((char*)Bs + n * 128 + ((p * 16) ^ ((n & 7) << 4))) = v;
        }
        __syncthreads();
        // ---- compute: 2 x (8 ds_read_b128 + 16 mfma)
#pragma unroll
        for (int kk = 0; kk < 2; ++kk) {
            short8 af[4], bf[4];
            const int kb = kk * 64 + ((lane >> 4) << 4);
#pragma unroll
            for (int mi = 0; mi < 4; ++mi) {
                int r = wm * 64 + mi * 16 + (lane & 15);
                af[mi] = *(const short8*)((char*)As + r * 128 + (kb ^ ((r & 7) << 4)));
            }
#pragma unroll
            for (int ni = 0; ni < 4; ++ni) {
                int n = wn * 64 + ni * 16 + (lane & 15);
                bf[ni] = *(const short8*)((char*)Bs + n * 128 + (kb ^ ((n & 7) << 4)));
            }
#pragma unroll
            for (int mi = 0; mi < 4; ++mi)
#pragma unroll
                for (int ni = 0; ni < 4; ++ni)
                    // swapped operands: D[n][m] layout -> lane holds 4 consecutive n-cols
                    acc[mi][ni] = __builtin_amdgcn_mfma_f32_16x16x32_bf16(
                        bf[ni], af[mi], acc[mi][ni], 0, 0, 0);
        }
        __syncthreads();
    }

    // store: m = m0 + wm*64 + mi*16 + (lane&15), n = wn*64 + ni*16 + (lane>>4)*4 + reg
    const int mrow = wm * 64 + (lane & 15);
    const int nb0  = wn * 64 + ((lane >> 4) << 2);
#pragma unroll
    for (int mi = 0; mi < 4; ++mi) {
        size_t mg = (size_t)(m0 + mrow + mi * 16);
#pragma unroll
        for (int ni = 0; ni < 4; ++ni) {
            f32x4 a = acc[mi][ni];
            ushort4 w;
            w.x = f32_to_bf16(a[0]); w.y = f32_to_bf16(a[1]);
            w.z = f32_to_bf16(a[2]); w.w = f32_to_bf16(a[3]);
            *(ushort4*)(Out + mg * HIDDEN + nb0 + ni * 16) = w;
        }
    }
}

// out[e] = relu(P[s]+Q[d]+b1) . W2 + b2 ; one wave per edge, lane j owns dims 4j..4j+3
__global__ __launch_bounds__(256) void edge_mlp(const unsigned short* __restrict__ P,
                                                const unsigned short* __restrict__ Q,
                                                const int* __restrict__ s_idx,
                                                const int* __restrict__ d_idx,
                                                const float* __restrict__ b1,
                                                const float* __restrict__ W2,
                                                const float* __restrict__ b2,
                                                float* __restrict__ out) {
    const int lane = threadIdx.x & 63;
    const int gw = (blockIdx.x * blockDim.x + threadIdx.x) >> 6;
    const int nw = (gridDim.x * blockDim.x) >> 6;
    const float4 b1v = *(const float4*)(b1 + lane * 4);
    const float4 w2v = *(const float4*)(W2 + lane * 4);
    const float b2s = *b2;
    for (int e = gw; e < N_EDGES; e += nw) {
        int s = s_idx[e];
        int d = d_idx[e];
        ushort4 pv = *(const ushort4*)(P + (size_t)s * HIDDEN + lane * 4);
        ushort4 qv = *(const ushort4*)(Q + (size_t)d * HIDDEN + lane * 4);
        float h, sum;
        h = bf16_to_f32(pv.x) + bf16_to_f32(qv.x) + b1v.x; h = fmaxf(h, 0.f); sum  = h * w2v.x;
        h = bf16_to_f32(pv.y) + bf16_to_f32(qv.y) + b1v.y; h = fmaxf(h, 0.f); sum += h * w2v.y;
        h = bf16_to_f32(pv.z) + bf16_to_f32(qv.z) + b1v.z; h = fmaxf(h, 0.f); sum += h * w2v.z;
        h = bf16_to_f32(pv.w) + bf16_to_f32(qv.w) + b1v.w; h = fmaxf(h, 0.f); sum += h * w2v.w;
#pragma unroll
        for (int off = 32; off; off >>= 1) sum += __shfl_xor(sum, off, 64);
        if (lane == 0) out[e] = sum + b2s;
    }
}

extern "C" void kernel_launch(void* const* d_in, const int* in_sizes, int n_in,
                              void* d_out, int out_size, void* d_ws, size_t ws_size,
                              hipStream_t stream) {
    const float* x_src = (const float*)d_in[0];
    const float* x_dst = (const float*)d_in[1];
    const int*   s_idx = (const int*)d_in[2];
    const int*   d_idx = (const int*)d_in[3];
    const float* W1    = (const float*)d_in[4];
    const float* b1    = (const float*)d_in[5];
    const float* W2    = (const float*)d_in[6];
    const float* b2    = (const float*)d_in[7];
    float* out = (float*)d_out;

    char* ws = (char*)d_ws;
    // layout: Wt (786432 B) | P (M_PAD*256*2 B) | Q (M_PAD*256*2 B)  => ~103.3 MB
    unsigned short* Wt = (unsigned short*)ws;
    unsigned short* P  = (unsigned short*)(ws + 786432);
    unsigned short* Q  = (unsigned short*)(ws + 786432 + (size_t)M_PAD * HIDDEN * 2);

    convert_w1<<<(2 * IN_DIM * HIDDEN + 255) / 256, 256, 0, stream>>>(W1, Wt);

    dim3 gg(M_BLOCKS, 2);
    node_gemm<<<gg, 512, 0, stream>>>(x_src, x_dst, Wt, P, Q);

    edge_mlp<<<2048, 256, 0, stream>>>(P, Q, s_idx, d_idx, b1, W2, b2, out);
}

// Round 2
// 233.426 us; speedup vs baseline: 1.3358x; 1.3358x over previous
//
#include <hip/hip_runtime.h>
#include <hip/hip_bf16.h>

#define N_NODES 100000
#define N_EDGES 262144
#define IN_DIM 768
#define HIDDEN 256
#define BM 128
#define BN 256
#define BK 64
#define NK (IN_DIM / BK)      // 12
#define M_BLOCKS 782          // ceil(100000/128)
#define M_PAD (M_BLOCKS * BM) // 100096

typedef __attribute__((ext_vector_type(8))) short short8;
typedef __attribute__((ext_vector_type(4))) float f32x4;

__device__ __forceinline__ unsigned short f32_to_bf16(float f) {
    unsigned int u = __builtin_bit_cast(unsigned int, f);
    u = (u + 0x7FFFu + ((u >> 16) & 1u)) >> 16;
    return (unsigned short)u;
}
__device__ __forceinline__ float bf16_to_f32(unsigned short h) {
    unsigned int u = ((unsigned int)h) << 16;
    return __builtin_bit_cast(float, u);
}

// Wt[g][n][k] = bf16(W1[g*768 + k][n]) ; k-contiguous for 16B fragment reads
__global__ __launch_bounds__(256) void convert_w1(const float* __restrict__ W1,
                                                  unsigned short* __restrict__ Wt) {
    int t = blockIdx.x * blockDim.x + threadIdx.x;
    if (t >= 2 * HIDDEN * IN_DIM) return;
    int k = t % IN_DIM;
    int n = (t / IN_DIM) % HIDDEN;
    int g = t / (IN_DIM * HIDDEN);
    Wt[t] = f32_to_bf16(W1[(size_t)(g * IN_DIM + k) * HIDDEN + n]);
}

// One 128x256 output tile of P = bf16(X) @ bf16(W1half). K = 768.
// blockIdx.y selects (x_src, W1[:768], P) vs (x_dst, W1[768:], Q).
// T14 async-STAGE split: global loads for tile k+1 issued BEFORE compute on
// tile k; convert+ds_write AFTER the post-compute barrier.
__global__ __launch_bounds__(512) void node_gemm(const float* __restrict__ X0,
                                                 const float* __restrict__ X1,
                                                 const unsigned short* __restrict__ WtAll,
                                                 unsigned short* __restrict__ Pout,
                                                 unsigned short* __restrict__ Qout) {
    const int g = blockIdx.y;
    const float* __restrict__ X = g ? X1 : X0;
    const unsigned short* __restrict__ Wt = WtAll + (size_t)g * IN_DIM * HIDDEN;
    unsigned short* __restrict__ Out = g ? Qout : Pout;

    // swizzled tiles: byte ^= ((row&7)<<4), row stride 128B
    __shared__ unsigned short As[BM * BK]; // [128][64] bf16, 16KB
    __shared__ unsigned short Bs[BN * BK]; // [256][64] bf16 (n-major, k-contig), 32KB

    const int m0   = blockIdx.x * BM;
    const int tid  = threadIdx.x;
    const int lane = tid & 63;
    const int wid  = tid >> 6;
    const int wm   = wid >> 2; // 0..1 -> 64-row slab
    const int wn   = wid & 3;  // 0..3 -> 64-col slab

    // per-thread staging addresses (A: row r, float4 p; B: n-row, 16B chunk p)
    const int ar = tid >> 4;           // 0..31 base row step per pass: +32
    const int ap = tid & 15;
    const int bn = tid >> 3;           // 0..63 base n step per pass: +64
    const int bp = tid & 7;

    f32x4 acc[4][4] = {};
    float4 areg[4];
    short8 breg[4];

    auto load_regs = [&](int ks) {
        const int k0 = ks * BK;
#pragma unroll
        for (int pass = 0; pass < 4; ++pass) {
            int r = ar + pass * 32;
            int rg = m0 + r;
            if (rg >= N_NODES) rg = N_NODES - 1; // clamp (pad rows get copies)
            areg[pass] = *(const float4*)(X + (size_t)rg * IN_DIM + k0 + ap * 4);
        }
#pragma unroll
        for (int pass = 0; pass < 4; ++pass) {
            int n = bn + pass * 64;
            breg[pass] = *(const short8*)(Wt + (size_t)n * IN_DIM + k0 + bp * 8);
        }
    };
    auto write_lds = [&]() {
#pragma unroll
        for (int pass = 0; pass < 4; ++pass) {
            int r = ar + pass * 32;
            float4 v = areg[pass];
            ushort4 w;
            w.x = f32_to_bf16(v.x); w.y = f32_to_bf16(v.y);
            w.z = f32_to_bf16(v.z); w.w = f32_to_bf16(v.w);
            *(ushort4*)((char*)As + r * 128 + ((ap * 8) ^ ((r & 7) << 4))) = w;
        }
#pragma unroll
        for (int pass = 0; pass < 4; ++pass) {
            int n = bn + pass * 64;
            *(short8*)((char*)Bs + n * 128 + ((bp * 16) ^ ((n & 7) << 4))) = breg[pass];
        }
    };
    auto compute = [&]() {
#pragma unroll
        for (int kk = 0; kk < 2; ++kk) {
            short8 af[4], bfr[4];
            const int kb = kk * 64 + ((lane >> 4) << 4);
#pragma unroll
            for (int mi = 0; mi < 4; ++mi) {
                int r = wm * 64 + mi * 16 + (lane & 15);
                af[mi] = *(const short8*)((char*)As + r * 128 + (kb ^ ((r & 7) << 4)));
            }
#pragma unroll
            for (int ni = 0; ni < 4; ++ni) {
                int n = wn * 64 + ni * 16 + (lane & 15);
                bfr[ni] = *(const short8*)((char*)Bs + n * 128 + (kb ^ ((n & 7) << 4)));
            }
#pragma unroll
            for (int mi = 0; mi < 4; ++mi)
#pragma unroll
                for (int ni = 0; ni < 4; ++ni)
                    // swapped operands: D[n][m] layout -> lane holds 4 consecutive n-cols
                    acc[mi][ni] = __builtin_amdgcn_mfma_f32_16x16x32_bf16(
                        bfr[ni], af[mi], acc[mi][ni], 0, 0, 0);
        }
    };

    // prologue: stage tile 0
    load_regs(0);
    write_lds();
    __syncthreads();
    for (int ks = 0; ks < NK - 1; ++ks) {
        load_regs(ks + 1);   // HBM latency hides under compute()
        compute();
        __syncthreads();     // all waves done reading LDS tile ks
        write_lds();         // waits vmcnt here, mostly already landed
        __syncthreads();
    }
    compute();               // last tile

    // store: m = m0 + wm*64 + mi*16 + (lane&15), n = wn*64 + ni*16 + (lane>>4)*4 + reg
    const int mrow = wm * 64 + (lane & 15);
    const int nb0  = wn * 64 + ((lane >> 4) << 2);
#pragma unroll
    for (int mi = 0; mi < 4; ++mi) {
        size_t mg = (size_t)(m0 + mrow + mi * 16);
#pragma unroll
        for (int ni = 0; ni < 4; ++ni) {
            f32x4 a = acc[mi][ni];
            ushort4 w;
            w.x = f32_to_bf16(a[0]); w.y = f32_to_bf16(a[1]);
            w.z = f32_to_bf16(a[2]); w.w = f32_to_bf16(a[3]);
            *(ushort4*)(Out + mg * HIDDEN + nb0 + ni * 16) = w;
        }
    }
}

// out[e] = relu(P[s]+Q[d]+b1) . W2 + b2 ; one wave per edge, lane j owns dims 4j..4j+3
__global__ __launch_bounds__(256) void edge_mlp(const unsigned short* __restrict__ P,
                                                const unsigned short* __restrict__ Q,
                                                const int* __restrict__ s_idx,
                                                const int* __restrict__ d_idx,
                                                const float* __restrict__ b1,
                                                const float* __restrict__ W2,
                                                const float* __restrict__ b2,
                                                float* __restrict__ out) {
    const int lane = threadIdx.x & 63;
    const int gw = (blockIdx.x * blockDim.x + threadIdx.x) >> 6;
    const int nw = (gridDim.x * blockDim.x) >> 6;
    const float4 b1v = *(const float4*)(b1 + lane * 4);
    const float4 w2v = *(const float4*)(W2 + lane * 4);
    const float b2s = *b2;
    for (int e = gw; e < N_EDGES; e += nw) {
        int s = s_idx[e];
        int d = d_idx[e];
        ushort4 pv = *(const ushort4*)(P + (size_t)s * HIDDEN + lane * 4);
        ushort4 qv = *(const ushort4*)(Q + (size_t)d * HIDDEN + lane * 4);
        float h, sum;
        h = bf16_to_f32(pv.x) + bf16_to_f32(qv.x) + b1v.x; h = fmaxf(h, 0.f); sum  = h * w2v.x;
        h = bf16_to_f32(pv.y) + bf16_to_f32(qv.y) + b1v.y; h = fmaxf(h, 0.f); sum += h * w2v.y;
        h = bf16_to_f32(pv.z) + bf16_to_f32(qv.z) + b1v.z; h = fmaxf(h, 0.f); sum += h * w2v.z;
        h = bf16_to_f32(pv.w) + bf16_to_f32(qv.w) + b1v.w; h = fmaxf(h, 0.f); sum += h * w2v.w;
#pragma unroll
        for (int off = 32; off; off >>= 1) sum += __shfl_xor(sum, off, 64);
        if (lane == 0) out[e] = sum + b2s;
    }
}

extern "C" void kernel_launch(void* const* d_in, const int* in_sizes, int n_in,
                              void* d_out, int out_size, void* d_ws, size_t ws_size,
                              hipStream_t stream) {
    const float* x_src = (const float*)d_in[0];
    const float* x_dst = (const float*)d_in[1];
    const int*   s_idx = (const int*)d_in[2];
    const int*   d_idx = (const int*)d_in[3];
    const float* W1    = (const float*)d_in[4];
    const float* b1    = (const float*)d_in[5];
    const float* W2    = (const float*)d_in[6];
    const float* b2    = (const float*)d_in[7];
    float* out = (float*)d_out;

    char* ws = (char*)d_ws;
    // layout: Wt (786432 B) | P (M_PAD*256*2 B) | Q (M_PAD*256*2 B)  => ~103.3 MB
    unsigned short* Wt = (unsigned short*)ws;
    unsigned short* P  = (unsigned short*)(ws + 786432);
    unsigned short* Q  = (unsigned short*)(ws + 786432 + (size_t)M_PAD * HIDDEN * 2);

    convert_w1<<<(2 * IN_DIM * HIDDEN + 255) / 256, 256, 0, stream>>>(W1, Wt);

    dim3 gg(M_BLOCKS, 2);
    node_gemm<<<gg, 512, 0, stream>>>(x_src, x_dst, Wt, P, Q);

    edge_mlp<<<2048, 256, 0, stream>>>(P, Q, s_idx, d_idx, b1, W2, b2, out);
}